// Round 1
// baseline (20.527 us; speedup 1.0000x reference)
//
#include <hip/hip_runtime.h>
#include <math.h>

#define NQ   12
#define DIM  4096      // 2^12
#define BATCH 512

// One block per batch element. State lives in LDS; 12 single-qubit
// butterfly passes implement U = kron(G0..G11) @ state exactly.
__global__ __launch_bounds__(256) void u3_apply_kernel(
    const float* __restrict__ thetas,   // [12,3]
    const float* __restrict__ sre,      // [512,4096]
    const float* __restrict__ sim_,     // [512,4096]
    float*       __restrict__ out)      // [512,4096,2] (re,im interleaved)
{
    __shared__ float re[DIM];
    __shared__ float im[DIM];
    __shared__ float g[NQ][8];  // g00r,g00i, g01r,g01i, g10r,g10i, g11r,g11i

    const int b = blockIdx.x;
    const int t = threadIdx.x;

    // ---- compute gates (threads 0..11) ----
    if (t < NQ) {
        float th = thetas[t * 3 + 0];
        float ph = thetas[t * 3 + 1];
        float la = thetas[t * 3 + 2];
        float c, s, cl, sl, cp, sp;
        __sincosf(th * 0.5f, &s, &c);
        __sincosf(la, &sl, &cl);
        __sincosf(ph, &sp, &cp);
        // U3 = [[c, -e^{i la} s], [e^{i ph} s, e^{i(ph+la)} c]]
        g[t][0] = c;        g[t][1] = 0.0f;
        g[t][2] = -cl * s;  g[t][3] = -sl * s;
        g[t][4] = cp * s;   g[t][5] = sp * s;
        float cpl = cp * cl - sp * sl;
        float spl = sp * cl + cp * sl;
        g[t][6] = cpl * c;  g[t][7] = spl * c;
    }

    // ---- load state into LDS (coalesced float4) ----
    const float4* sre4 = (const float4*)(sre + (size_t)b * DIM);
    const float4* sim4 = (const float4*)(sim_ + (size_t)b * DIM);
    float4* re4 = (float4*)re;
    float4* im4 = (float4*)im;
#pragma unroll
    for (int k = 0; k < DIM / 4 / 256; ++k) {   // 4 iters
        int idx = k * 256 + t;
        re4[idx] = sre4[idx];
        im4[idx] = sim4[idx];
    }
    __syncthreads();

    // ---- 12 butterfly passes; gate q acts on bit (11 - q) ----
#pragma unroll
    for (int bit = 0; bit < NQ; ++bit) {
        const int q = NQ - 1 - bit;
        const float g00r = g[q][0], g00i = g[q][1];
        const float g01r = g[q][2], g01i = g[q][3];
        const float g10r = g[q][4], g10i = g[q][5];
        const float g11r = g[q][6], g11i = g[q][7];
        const int lowmask = (1 << bit) - 1;
#pragma unroll
        for (int k = 0; k < DIM / 2 / 256; ++k) {  // 8 pairs/thread
            int p  = k * 256 + t;                  // pair id 0..2047
            int i0 = ((p >> bit) << (bit + 1)) | (p & lowmask);
            int i1 = i0 | (1 << bit);
            float x0r = re[i0], x0i = im[i0];
            float x1r = re[i1], x1i = im[i1];
            float y0r = g00r * x0r - g00i * x0i + g01r * x1r - g01i * x1i;
            float y0i = g00r * x0i + g00i * x0r + g01r * x1i + g01i * x1r;
            float y1r = g10r * x0r - g10i * x0i + g11r * x1r - g11i * x1i;
            float y1i = g10r * x0i + g10i * x0r + g11r * x1i + g11i * x1r;
            re[i0] = y0r; im[i0] = y0i;
            re[i1] = y1r; im[i1] = y1i;
        }
        __syncthreads();
    }

    // ---- store interleaved (re, im) as float2 ----
    float2* o2 = (float2*)(out + (size_t)b * DIM * 2);
#pragma unroll
    for (int k = 0; k < DIM / 256; ++k) {   // 16 iters
        int i = k * 256 + t;
        o2[i] = make_float2(re[i], im[i]);
    }
}

extern "C" void kernel_launch(void* const* d_in, const int* in_sizes, int n_in,
                              void* d_out, int out_size, void* d_ws, size_t ws_size,
                              hipStream_t stream) {
    const float* thetas = (const float*)d_in[0];   // [12,3]
    const float* sre    = (const float*)d_in[1];   // [512,4096,1]
    const float* sim_   = (const float*)d_in[2];   // [512,4096,1]
    float* out = (float*)d_out;                    // [512,4096,2]

    u3_apply_kernel<<<BATCH, 256, 0, stream>>>(thetas, sre, sim_, out);
}

// Round 2
// 15.824 us; speedup vs baseline: 1.2972x; 1.2972x over previous
//
#include <hip/hip_runtime.h>
#include <math.h>

#define NQ    12
#define DIM   4096
#define BATCH 512

// padded LDS index: +1 float per 32 -> all three exchange patterns are
// exactly 2-way bank aliased (free on gfx950)
#define PADF(i) ((i) + ((i) >> 5))

// One butterfly level over the 16 register-resident amplitudes.
// J = local bit (0..3), q = gate index into g[][]. J must be a literal so
// the unrolled indices are compile-time constants (no scratch spill).
#define STAGE_LEVEL(q, J) do {                                              \
    const float G00r = g[q][0], G00i = g[q][1];                             \
    const float G01r = g[q][2], G01i = g[q][3];                             \
    const float G10r = g[q][4], G10i = g[q][5];                             \
    const float G11r = g[q][6], G11i = g[q][7];                             \
    _Pragma("unroll")                                                       \
    for (int p = 0; p < 8; ++p) {                                           \
        const int r0 = ((p >> (J)) << ((J) + 1)) | (p & ((1 << (J)) - 1));  \
        const int r1 = r0 | (1 << (J));                                     \
        const float ar = xr[r0], ai = xi[r0];                               \
        const float br = xr[r1], bi = xi[r1];                               \
        xr[r0] = G00r * ar - G00i * ai + G01r * br - G01i * bi;             \
        xi[r0] = G00r * ai + G00i * ar + G01r * bi + G01i * br;             \
        xr[r1] = G10r * ar - G10i * ai + G11r * br - G11i * bi;             \
        xi[r1] = G10r * ai + G10i * ar + G11r * bi + G11i * br;             \
    }                                                                       \
} while (0)

__global__ __launch_bounds__(256) void u3_apply_kernel(
    const float* __restrict__ thetas,   // [12,3]
    const float* __restrict__ sre,      // [512,4096]
    const float* __restrict__ sim_,     // [512,4096]
    float*       __restrict__ out)      // [512,4096,2]
{
    __shared__ float lre[4224];         // PADF(4095)+1 = 4223, rounded
    __shared__ float lim[4224];
    __shared__ float g[NQ][8];

    const int b = blockIdx.x;
    const int t = threadIdx.x;

    // ---- gates (threads 0..11) ----
    if (t < NQ) {
        float th = thetas[t * 3 + 0];
        float ph = thetas[t * 3 + 1];
        float la = thetas[t * 3 + 2];
        float c, s, cl, sl, cp, sp;
        __sincosf(th * 0.5f, &s, &c);
        __sincosf(la, &sl, &cl);
        __sincosf(ph, &sp, &cp);
        g[t][0] = c;        g[t][1] = 0.0f;
        g[t][2] = -cl * s;  g[t][3] = -sl * s;
        g[t][4] = cp * s;   g[t][5] = sp * s;
        float cpl = cp * cl - sp * sl;
        float spl = sp * cl + cp * sl;
        g[t][6] = cpl * c;  g[t][7] = spl * c;
    }

    // ---- global -> registers: thread t owns idx = 16t + r (bits 3:0 local)
    float xr[16], xi[16];
    {
        const float4* pre = (const float4*)(sre  + (size_t)b * DIM + t * 16);
        const float4* pim = (const float4*)(sim_ + (size_t)b * DIM + t * 16);
#pragma unroll
        for (int k = 0; k < 4; ++k) {
            float4 vr = pre[k];
            float4 vi = pim[k];
            xr[4 * k + 0] = vr.x; xr[4 * k + 1] = vr.y;
            xr[4 * k + 2] = vr.z; xr[4 * k + 3] = vr.w;
            xi[4 * k + 0] = vi.x; xi[4 * k + 1] = vi.y;
            xi[4 * k + 2] = vi.z; xi[4 * k + 3] = vi.w;
        }
    }
    __syncthreads();   // gates ready

    // ---- stage A: index bits 0..3 -> gates q = 11,10,9,8 ----
    STAGE_LEVEL(11, 0);
    STAGE_LEVEL(10, 1);
    STAGE_LEVEL(9, 2);
    STAGE_LEVEL(8, 3);

    // exchange 1: write A-pattern, read B-pattern
#pragma unroll
    for (int r = 0; r < 16; ++r) {
        const int idx = t * 16 + r;
        lre[PADF(idx)] = xr[r];
        lim[PADF(idx)] = xi[r];
    }
    __syncthreads();
    {
        const int hi = t >> 4, lo = t & 15;
#pragma unroll
        for (int r = 0; r < 16; ++r) {
            const int idx = (hi << 8) | (r << 4) | lo;
            xr[r] = lre[PADF(idx)];
            xi[r] = lim[PADF(idx)];
        }
    }

    // ---- stage B: index bits 4..7 -> gates q = 7,6,5,4 ----
    STAGE_LEVEL(7, 0);
    STAGE_LEVEL(6, 1);
    STAGE_LEVEL(5, 2);
    STAGE_LEVEL(4, 3);

    // exchange 2: write B-pattern, read C-pattern
    __syncthreads();   // all exchange-1 reads done before overwrite
    {
        const int hi = t >> 4, lo = t & 15;
#pragma unroll
        for (int r = 0; r < 16; ++r) {
            const int idx = (hi << 8) | (r << 4) | lo;
            lre[PADF(idx)] = xr[r];
            lim[PADF(idx)] = xi[r];
        }
    }
    __syncthreads();
#pragma unroll
    for (int r = 0; r < 16; ++r) {
        const int idx = (r << 8) | t;
        xr[r] = lre[PADF(idx)];
        xi[r] = lim[PADF(idx)];
    }

    // ---- stage C: index bits 8..11 -> gates q = 3,2,1,0 ----
    STAGE_LEVEL(3, 0);
    STAGE_LEVEL(2, 1);
    STAGE_LEVEL(1, 2);
    STAGE_LEVEL(0, 3);

    // ---- store: idx = (r<<8)|t -> consecutive across lanes, float2 ----
    {
        float2* o2 = (float2*)(out + (size_t)b * DIM * 2);
#pragma unroll
        for (int r = 0; r < 16; ++r) {
            const int idx = (r << 8) | t;
            o2[idx] = make_float2(xr[r], xi[r]);
        }
    }
}

extern "C" void kernel_launch(void* const* d_in, const int* in_sizes, int n_in,
                              void* d_out, int out_size, void* d_ws, size_t ws_size,
                              hipStream_t stream) {
    const float* thetas = (const float*)d_in[0];
    const float* sre    = (const float*)d_in[1];
    const float* sim_   = (const float*)d_in[2];
    float* out = (float*)d_out;

    u3_apply_kernel<<<BATCH, 256, 0, stream>>>(thetas, sre, sim_, out);
}